// Round 19
// baseline (102.890 us; speedup 1.0000x reference)
//
#include <hip/hip_runtime.h>
#include <math.h>

#define NB 8
#define NS 512
#define NE 32
#define DE 256
#define DH 512
#define DA 200
#define DAP 224   // padded att dim (7 tiles of 32)
#define NJ 7

typedef __bf16 bf16x8 __attribute__((ext_vector_type(8)));
typedef float f32x16 __attribute__((ext_vector_type(16)));

__device__ __forceinline__ float tanh_fast(float x) {
    float e = __expf(x + x);
    return fmaf(-2.f, __builtin_amdgcn_rcpf(e + 1.f), 1.f);
}

// ---- stage 1: partial sums of cxt over s-chunks (512 blocks) ----
__global__ __launch_bounds__(256) void cmean_partial(const float* __restrict__ cxt,
                                                     float* __restrict__ psum) {
    const int g = blockIdx.x;       // b*64 + c
    const int b = g >> 6, c = g & 63;
    const int t = threadIdx.x;
    const float* base = cxt + ((size_t)b * NS + c * 8) * DH;
    float s0 = 0.f, s1 = 0.f;
    #pragma unroll
    for (int s = 0; s < 8; ++s) {
        s0 += base[s * DH + t];
        s1 += base[s * DH + t + 256];
    }
    psum[(size_t)g * DH + t]       = s0;
    psum[(size_t)g * DH + t + 256] = s1;
}

// ---- stage 2: reduce partials -> cmean; hatt[b][a] = cmean @ Wh (zero-padded) ----
__global__ __launch_bounds__(256) void hatt_from_psum(const float* __restrict__ psum,
                                                      const float* __restrict__ Wh,
                                                      float* __restrict__ hattw) {
    const int b = blockIdx.x;
    const int t = threadIdx.x;
    __shared__ float cm[DH];
    float s0 = 0.f, s1 = 0.f;
    for (int c = 0; c < 64; ++c) {
        s0 += psum[((size_t)b * 64 + c) * DH + t];
        s1 += psum[((size_t)b * 64 + c) * DH + t + 256];
    }
    cm[t]       = s0 * (1.f / NS);
    cm[t + 256] = s1 * (1.f / NS);
    __syncthreads();
    if (t < DAP) {
        float acc = 0.f;
        if (t < DA)
            for (int h = 0; h < DH; ++h)
                acc = fmaf(cm[h], Wh[h * DA + t], acc);
        hattw[b * DAP + t] = acc;
    }
}

// ---- stage 3: pack We into bf16 B-fragment layout (zero-padded cols) ----
__global__ __launch_bounds__(64) void wef_build(const float* __restrict__ We,
                                                __bf16* __restrict__ wef) {
    const int f = blockIdx.x;
    const int l = threadIdx.x;
    const int nj = f >> 4, kk = f & 15;
    const int n = nj * 32 + (l & 31);
    bf16x8 v;
    #pragma unroll
    for (int e = 0; e < 8; ++e) {
        int K = kk * 16 + ((l >> 5) << 2) + (e & 3) + 8 * (e >> 2);
        v[e] = (__bf16)((n < DA) ? We[K * DA + n] : 0.f);
    }
    reinterpret_cast<bf16x8*>(wef)[f * 64 + l] = v;
}

// ---- main: 4096 small blocks (1 tile each, 256 thr) — the fast-kernel grid
// shape. Contiguous 32KB staging (r2's proven pattern) into XOR-swizzled LDS;
// MFMA A-frags gathered from LDS (4-way max conflicts); B-frags streamed from
// L2-hot wef (r11 path); fp32 epilogue from LDS (no global re-read).
// ~33KB LDS + ~100 VGPR -> ~4 independent blocks/CU at decorrelated phases.
__global__ __launch_bounds__(256) void entatt_main(const float* __restrict__ ent,
                                                   const __bf16* __restrict__ wef,
                                                   const float* __restrict__ hattw,
                                                   const float* __restrict__ Ws,
                                                   float* __restrict__ out) {
    const int t    = threadIdx.x;
    const int lane = t & 63;
    const int te   = t >> 6;            // wave 0..3
    const int m    = lane & 31;
    const int hi   = lane >> 5;
    const int bs   = blockIdx.x;        // one (b,s) tile per block
    const int b    = bs >> 9;           // NS = 512

    __shared__ float L[32 * 256];       // 32 KB tile, quad-XOR-swizzled
    __shared__ float partials[4][NE];

    // ---- stage: contiguous float4 reads, swizzled LDS writes ----
    // quad slot of (row mm, quad c) = c ^ (mm & 7)  [bijective per row]
    {
        const float4* s4 = reinterpret_cast<const float4*>(ent + (size_t)bs * 8192);
        float4* l4 = reinterpret_cast<float4*>(L);
        #pragma unroll
        for (int k = 0; k < 8; ++k) {
            float4 v = s4[t + k * 256];            // contiguous across block
            const int f4 = t + k * 256;
            const int mm = f4 >> 6, c = f4 & 63;
            l4[mm * 64 + (c ^ (mm & 7))] = v;
        }
    }

    // ---- this wave's nj assignment: waves 0-2 -> {2w,2w+1}, wave 3 -> {6} ----
    const int nj0 = (te < 3) ? 2 * te : 6;
    const bool has1 = (te < 3);
    const int nj1 = has1 ? 2 * te + 1 : 6;
    const int a0 = nj0 * 32 + m, a1 = nj1 * 32 + m;
    const float ha0 = hattw[b * DAP + a0];
    const float ws0 = (a0 < DA) ? Ws[a0] : 0.f;
    const float ha1 = has1 ? hattw[b * DAP + a1] : 0.f;
    const float ws1 = (has1 && a1 < DA) ? Ws[a1] : 0.f;

    __syncthreads();   // tile staged

    // ---- MFMA: A-frag gathered from swizzled LDS, B streamed from L2 ----
    const bf16x8* wg8 = reinterpret_cast<const bf16x8*>(wef);
    const float4* el4 = reinterpret_cast<const float4*>(L);
    f32x16 acc0, acc1;
    #pragma unroll
    for (int q = 0; q < 16; ++q) { acc0[q] = 0.f; acc1[q] = 0.f; }

    #pragma unroll
    for (int kk = 0; kk < 16; ++kk) {
        const int qa = 4 * kk + hi;                       // true quad of elems 0-3
        float4 p0 = el4[m * 64 + (qa ^ (m & 7))];
        float4 p1 = el4[m * 64 + ((qa + 2) ^ (m & 7))];   // elems 4-7 quad
        bf16x8 fr = { (__bf16)p0.x, (__bf16)p0.y, (__bf16)p0.z, (__bf16)p0.w,
                      (__bf16)p1.x, (__bf16)p1.y, (__bf16)p1.z, (__bf16)p1.w };
        acc0 = __builtin_amdgcn_mfma_f32_32x32x16_bf16(
                   fr, wg8[(nj0 * 16 + kk) * 64 + lane], acc0, 0, 0, 0);
        if (has1)
            acc1 = __builtin_amdgcn_mfma_f32_32x32x16_bf16(
                       fr, wg8[(nj1 * 16 + kk) * 64 + lane], acc1, 0, 0, 0);
    }

    // ---- logits: tanh, scale by Ws, reduce over 32 a-cols (lanes) ----
    float part[16];
    #pragma unroll
    for (int q = 0; q < 16; ++q) {
        float v = tanh_fast(acc0[q] + ha0) * ws0;
        if (has1) v += tanh_fast(acc1[q] + ha1) * ws1;
        v += __shfl_xor(v, 1);  v += __shfl_xor(v, 2);  v += __shfl_xor(v, 4);
        v += __shfl_xor(v, 8);  v += __shfl_xor(v, 16);
        part[q] = v;
    }
    if (m == 0) {
        #pragma unroll
        for (int q = 0; q < 16; ++q)
            partials[te][(q & 3) + 8 * (q >> 2) + 4 * hi] = part[q];
    }
    __syncthreads();   // partials ready

    // ---- softmax (r16 pattern: lane e owns entity e, shfl reduce) ----
    const int e0 = lane & 31;
    float lg = partials[0][e0] + partials[1][e0] + partials[2][e0] + partials[3][e0];
    float mx = lg;
    mx = fmaxf(mx, __shfl_xor(mx, 1));  mx = fmaxf(mx, __shfl_xor(mx, 2));
    mx = fmaxf(mx, __shfl_xor(mx, 4));  mx = fmaxf(mx, __shfl_xor(mx, 8));
    mx = fmaxf(mx, __shfl_xor(mx, 16));
    float ex = __expf(lg - mx);
    float sm = ex;
    sm += __shfl_xor(sm, 1);  sm += __shfl_xor(sm, 2);  sm += __shfl_xor(sm, 4);
    sm += __shfl_xor(sm, 8);  sm += __shfl_xor(sm, 16);
    const float wv = ex * __builtin_amdgcn_rcpf(sm);

    // ---- epilogue: weighted sum from swizzled LDS; thread t owns col d=t ----
    const int d = t;
    const int qd = d >> 2, ed = d & 3;
    float o = 0.f;
    #pragma unroll
    for (int e = 0; e < NE; ++e) {
        const float we = __shfl(wv, e);   // lane e of this wave holds entity e's weight
        o = fmaf(we, L[e * 256 + ((qd ^ (e & 7)) << 2) + ed], o);
    }
    out[(size_t)bs * 256 + d] = o;
}

extern "C" void kernel_launch(void* const* d_in, const int* in_sizes, int n_in,
                              void* d_out, int out_size, void* d_ws, size_t ws_size,
                              hipStream_t stream) {
    const float* cxt = (const float*)d_in[0];
    const float* ent = (const float*)d_in[1];
    const float* We  = (const float*)d_in[2];
    const float* Wh  = (const float*)d_in[3];
    const float* Ws  = (const float*)d_in[4];
    float* out = (float*)d_out;

    float*  psum  = (float*)d_ws;                       // 512*512 f32 = 1 MB
    float*  hattw = psum + 512 * DH;                    // 8*224 f32
    __bf16* wef   = (__bf16*)(hattw + NB * DAP);        // 7*16*512 bf16 = 112 KB

    hipLaunchKernelGGL(wef_build, dim3(NJ * 16), dim3(64), 0, stream, We, wef);
    hipLaunchKernelGGL(cmean_partial, dim3(512), dim3(256), 0, stream, cxt, psum);
    hipLaunchKernelGGL(hatt_from_psum, dim3(NB), dim3(256), 0, stream, psum, Wh, hattw);
    hipLaunchKernelGGL(entatt_main, dim3(NB * NS), dim3(256), 0, stream,
                       ent, wef, hattw, Ws, out);
}